// Round 2
// baseline (936.290 us; speedup 1.0000x reference)
//
#include <hip/hip_runtime.h>
#include <stdint.h>

typedef float f4 __attribute__((ext_vector_type(4)));

// One thread handles 8 consecutive pairs p..p+7 (8 | n_mm, so the image s and
// the ML atom i are uniform within a thread). Output dtype is FLOAT32 (the
// reference returns int32/float32/bool -> harness uses float*). Each thread
// writes 8 pairs * 16 floats = 512 B via 32 aligned 16-B stores.
__global__ __launch_bounds__(256) void nl_kernel(
    const float* __restrict__ pos,      // (n_ml+n_mm, 3)
    const float* __restrict__ cell,     // (3,3) row-major
    const float* __restrict__ cutoffs,  // (2,)
    const int*   __restrict__ shifts,   // (S,3)
    const int*   __restrict__ ml_idx,   // (n_ml,)
    const int*   __restrict__ mm_idx,   // (n_mm,)
    float* __restrict__ out,            // float32, 16P elements
    int n_mm, int P0, int P)
{
    int tid = blockIdx.x * blockDim.x + threadIdx.x;
    int p = tid << 3;
    if (p >= P) return;

    int s     = p / P0;                 // image index 0..S
    int a     = p - s * P0;             // pair index within image
    int i_idx = a / n_mm;               // ML slot (uniform over the 8 pairs)
    int j0    = a - i_idx * n_mm;       // first MM slot

    int pi = ml_idx[i_idx];
    float xi = pos[3 * pi + 0], yi = pos[3 * pi + 1], zi = pos[3 * pi + 2];

    // shift_frac row: image 0 is the zero shift, images 1..S are shifts[s-1]
    int sx = 0, sy = 0, sz = 0;
    if (s > 0) {
        sx = shifts[3 * (s - 1) + 0];
        sy = shifts[3 * (s - 1) + 1];
        sz = shifts[3 * (s - 1) + 2];
    }
    float fx = (float)sx, fy = (float)sy, fz = (float)sz;
    // shift_vec = shift_frac @ cell (accumulate rows in numpy order, no fma)
    float svx = __fadd_rn(__fadd_rn(__fmul_rn(fx, cell[0]), __fmul_rn(fy, cell[3])), __fmul_rn(fz, cell[6]));
    float svy = __fadd_rn(__fadd_rn(__fmul_rn(fx, cell[1]), __fmul_rn(fy, cell[4])), __fmul_rn(fz, cell[7]));
    float svz = __fadd_rn(__fadd_rn(__fmul_rn(fx, cell[2]), __fmul_rn(fy, cell[5])), __fmul_rn(fz, cell[8]));

    float c0 = __fmul_rn(cutoffs[0], cutoffs[0]);
    float c1 = __fmul_rn(cutoffs[1], cutoffs[1]);

    float fI = (float)pi;
    float vJ[8], vD[8], vM0[8], vM1[8];

#pragma unroll
    for (int k = 0; k < 8; ++k) {
        int pj = mm_idx[j0 + k];
        float xj = pos[3 * pj + 0], yj = pos[3 * pj + 1], zj = pos[3 * pj + 2];
        // Rij = (pos_i - pos_j) + shift_vec, fp32 ops in reference order (no fma)
        float dx = __fadd_rn(__fsub_rn(xi, xj), svx);
        float dy = __fadd_rn(__fsub_rn(yi, yj), svy);
        float dz = __fadd_rn(__fsub_rn(zi, zj), svz);
        float d2 = __fadd_rn(__fadd_rn(__fmul_rn(dx, dx), __fmul_rn(dy, dy)), __fmul_rn(dz, dz));
        vJ[k]  = (float)pj;
        vD[k]  = d2;
        vM0[k] = (d2 < c0) ? 1.0f : 0.0f;
        vM1[k] = (d2 < c1) ? 1.0f : 0.0f;
    }

    f4 vIa = {fI, fI, fI, fI};
    f4 vJa = {vJ[0], vJ[1], vJ[2], vJ[3]},   vJb = {vJ[4], vJ[5], vJ[6], vJ[7]};
    f4 vDa = {vD[0], vD[1], vD[2], vD[3]},   vDb = {vD[4], vD[5], vD[6], vD[7]};
    f4 vM0a = {vM0[0], vM0[1], vM0[2], vM0[3]}, vM0b = {vM0[4], vM0[5], vM0[6], vM0[7]};
    f4 vM1a = {vM1[0], vM1[1], vM1[2], vM1[3]}, vM1b = {vM1[4], vM1[5], vM1[6], vM1[7]};

    // offsets_cart rows: first half = -shift_vec, second half = +shift_vec.
    // 8 rows of (x,y,z) = 24 floats = six 16-B chunks, 3 distinct patterns.
    float nx = -svx, ny = -svy, nz = -svz;
    f4 n0 = {nx,  ny,  nz,  nx }, n1 = {ny,  nz,  nx,  ny }, n2 = {nz,  nx,  ny,  nz };
    f4 p0 = {svx, svy, svz, svx}, p1 = {svy, svz, svx, svy}, p2 = {svz, svx, svy, svz};

    size_t Pz = (size_t)P;
    size_t pp = (size_t)p;
    // layout: [idx_i 2P][idx_j 2P][offsets 6P][d2 2P][masks 4P] (floats)
    f4* o;
    o = (f4*)(out + 0 * Pz + pp);  o[0] = vIa; o[1] = vIa;   // idx_i half1 (pi)
    o = (f4*)(out + 1 * Pz + pp);  o[0] = vJa; o[1] = vJb;   // idx_i half2 (pj)
    o = (f4*)(out + 2 * Pz + pp);  o[0] = vJa; o[1] = vJb;   // idx_j half1 (pj)
    o = (f4*)(out + 3 * Pz + pp);  o[0] = vIa; o[1] = vIa;   // idx_j half2 (pi)
    o = (f4*)(out + 4 * Pz + 3 * pp);                        // offsets rows p..p+7
    o[0] = n0; o[1] = n1; o[2] = n2; o[3] = n0; o[4] = n1; o[5] = n2;
    o = (f4*)(out + 7 * Pz + 3 * pp);                        // offsets rows P+p..
    o[0] = p0; o[1] = p1; o[2] = p2; o[3] = p0; o[4] = p1; o[5] = p2;
    o = (f4*)(out + 10 * Pz + pp); o[0] = vDa; o[1] = vDb;   // d2 half1
    o = (f4*)(out + 11 * Pz + pp); o[0] = vDa; o[1] = vDb;   // d2 half2
    o = (f4*)(out + 12 * Pz + pp); o[0] = vM0a; o[1] = vM0b; // mask c0, q in [0,P)
    o = (f4*)(out + 13 * Pz + pp); o[0] = vM0a; o[1] = vM0b; // mask c0, q in [P,2P)
    o = (f4*)(out + 14 * Pz + pp); o[0] = vM1a; o[1] = vM1b; // mask c1, q in [0,P)
    o = (f4*)(out + 15 * Pz + pp); o[0] = vM1a; o[1] = vM1b; // mask c1, q in [P,2P)
}

extern "C" void kernel_launch(void* const* d_in, const int* in_sizes, int n_in,
                              void* d_out, int out_size, void* d_ws, size_t ws_size,
                              hipStream_t stream) {
    const float* pos    = (const float*)d_in[0];
    const float* cell   = (const float*)d_in[1];
    const float* cut    = (const float*)d_in[2];
    const int*   shifts = (const int*)d_in[3];
    const int*   ml     = (const int*)d_in[4];
    const int*   mm     = (const int*)d_in[5];

    int n_ml = in_sizes[4];
    int n_mm = in_sizes[5];
    int S    = in_sizes[3] / 3;
    int P0   = n_ml * n_mm;          // 128*8192 = 1048576
    int P    = (S + 1) * P0;         // 14*P0 = 14,680,064 ; out_size == 16*P

    int threads = P / 8;             // 8 pairs per thread
    int grid = (threads + 255) / 256;
    nl_kernel<<<grid, 256, 0, stream>>>(pos, cell, cut, shifts, ml, mm,
                                        (float*)d_out, n_mm, P0, P);
}

// Round 3
// 910.146 us; speedup vs baseline: 1.0287x; 1.0287x over previous
//
#include <hip/hip_runtime.h>
#include <stdint.h>

typedef float f4 __attribute__((ext_vector_type(4)));

// phase-rotated (x,y,z) repeating pattern: t=0 -> {x,y,z,x}, t=1 -> {y,z,x,y},
// t=2 -> {z,x,y,z}. t is runtime (per-lane) -> compiler emits v_cndmask selects.
__device__ __forceinline__ f4 rot3(float x, float y, float z, int t) {
    float a0 = (t == 0) ? x : ((t == 1) ? y : z);
    float a1 = (t == 0) ? y : ((t == 1) ? z : x);
    float a2 = (t == 0) ? z : ((t == 1) ? x : y);
    f4 r = {a0, a1, a2, a0};
    return r;
}

// One thread handles 4 consecutive pairs p..p+3 (4 | n_mm). Every wave-level
// store instruction is fully lane-dense: 64 lanes x 16 B = 1 KB contiguous.
// Offsets (6P floats, 37.5% of traffic) use a wave-cooperative dense layout,
// valid because shift_vec is wave-uniform (each wave's 256 pairs are inside
// one periodic image: P0 = n_ml*n_mm is a multiple of 256).
__global__ __launch_bounds__(256) void nl_kernel(
    const float* __restrict__ pos,      // (n_ml+n_mm, 3)
    const float* __restrict__ cell,     // (3,3) row-major
    const float* __restrict__ cutoffs,  // (2,)
    const int*   __restrict__ shifts,   // (S,3)
    const int*   __restrict__ ml_idx,   // (n_ml,)
    const int*   __restrict__ mm_idx,   // (n_mm,)
    float* __restrict__ out,            // float32, 16P elements
    int n_mm, int P0, int P)
{
    int tid = blockIdx.x * blockDim.x + threadIdx.x;
    int p = tid << 2;                   // 4 pairs per thread
    if (p >= P) return;

    int s     = p / P0;                 // image index 0..S (wave-uniform)
    int a     = p - s * P0;             // pair index within image
    int i_idx = a / n_mm;               // ML slot (uniform over the 4 pairs)
    int j0    = a - i_idx * n_mm;       // first MM slot (multiple of 4)

    int pi = ml_idx[i_idx];
    float xi = pos[3 * pi + 0], yi = pos[3 * pi + 1], zi = pos[3 * pi + 2];

    // shift_frac row: image 0 is zero shift, images 1..S are shifts[s-1]
    int sx = 0, sy = 0, sz = 0;
    if (s > 0) {
        sx = shifts[3 * (s - 1) + 0];
        sy = shifts[3 * (s - 1) + 1];
        sz = shifts[3 * (s - 1) + 2];
    }
    float fx = (float)sx, fy = (float)sy, fz = (float)sz;
    // shift_vec = shift_frac @ cell, numpy accumulation order, no fma
    float svx = __fadd_rn(__fadd_rn(__fmul_rn(fx, cell[0]), __fmul_rn(fy, cell[3])), __fmul_rn(fz, cell[6]));
    float svy = __fadd_rn(__fadd_rn(__fmul_rn(fx, cell[1]), __fmul_rn(fy, cell[4])), __fmul_rn(fz, cell[7]));
    float svz = __fadd_rn(__fadd_rn(__fmul_rn(fx, cell[2]), __fmul_rn(fy, cell[5])), __fmul_rn(fz, cell[8]));

    float c0 = __fmul_rn(cutoffs[0], cutoffs[0]);
    float c1 = __fmul_rn(cutoffs[1], cutoffs[1]);

    float fI = (float)pi;
    f4 vI = {fI, fI, fI, fI};
    f4 vJ, vD, vM0, vM1;

    int4 pj4 = *(const int4*)(mm_idx + j0);   // j0 % 4 == 0 -> 16B aligned
    int pjs[4] = {pj4.x, pj4.y, pj4.z, pj4.w};
#pragma unroll
    for (int k = 0; k < 4; ++k) {
        int pj = pjs[k];
        float xj = pos[3 * pj + 0], yj = pos[3 * pj + 1], zj = pos[3 * pj + 2];
        // Rij = (pos_i - pos_j) + shift_vec, fp32 ops in reference order
        float dx = __fadd_rn(__fsub_rn(xi, xj), svx);
        float dy = __fadd_rn(__fsub_rn(yi, yj), svy);
        float dz = __fadd_rn(__fsub_rn(zi, zj), svz);
        float d2 = __fadd_rn(__fadd_rn(__fmul_rn(dx, dx), __fmul_rn(dy, dy)), __fmul_rn(dz, dz));
        vJ[k]  = (float)pj;
        vD[k]  = d2;
        vM0[k] = (d2 < c0) ? 1.0f : 0.0f;
        vM1[k] = (d2 < c1) ? 1.0f : 0.0f;
    }

    size_t Pz = (size_t)P;
    size_t pp = (size_t)p;
    // layout: [idx_i 2P][idx_j 2P][offsets 6P][d2 2P][masks 4P] (floats)
    *(f4*)(out + 0 * Pz + pp)  = vI;    // idx_i, q in [0,P)    (pi)
    *(f4*)(out + 1 * Pz + pp)  = vJ;    // idx_i, q in [P,2P)   (pj)
    *(f4*)(out + 2 * Pz + pp)  = vJ;    // idx_j, q in [0,P)    (pj)
    *(f4*)(out + 3 * Pz + pp)  = vI;    // idx_j, q in [P,2P)   (pi)
    *(f4*)(out + 10 * Pz + pp) = vD;    // d2, q in [0,P)
    *(f4*)(out + 11 * Pz + pp) = vD;    // d2, q in [P,2P)
    *(f4*)(out + 12 * Pz + pp) = vM0;   // mask c0, q in [0,P)
    *(f4*)(out + 13 * Pz + pp) = vM0;   // mask c0, q in [P,2P)
    *(f4*)(out + 14 * Pz + pp) = vM1;   // mask c1, q in [0,P)
    *(f4*)(out + 15 * Pz + pp) = vM1;   // mask c1, q in [P,2P)

    // ---- offsets: wave-cooperative dense stores ----
    int lane = (int)(threadIdx.x & 63);
    size_t pw = pp - (size_t)(lane << 2);       // wave's first pair index
    float nx = -svx, ny = -svy, nz = -svz;
    float* nb = out + 4 * Pz + 3 * pw;          // -shift half, wave 3KB region
    float* qb = out + 7 * Pz + 3 * pw;          // +shift half

    if (pw + 256 <= (size_t)P) {                // full wave (always, here)
#pragma unroll
        for (int c = 0; c < 3; ++c) {
            int t = (lane + c) % 3;             // float-phase of this chunk
            *(f4*)(nb + c * 256 + 4 * lane) = rot3(nx, ny, nz, t);
            *(f4*)(qb + c * 256 + 4 * lane) = rot3(svx, svy, svz, t);
        }
    } else {                                    // safety net for partial wave
        float* n0 = out + 4 * Pz + 3 * pp;
        float* q0 = out + 7 * Pz + 3 * pp;
#pragma unroll
        for (int r = 0; r < 4; ++r) {
            n0[3*r+0] = nx;  n0[3*r+1] = ny;  n0[3*r+2] = nz;
            q0[3*r+0] = svx; q0[3*r+1] = svy; q0[3*r+2] = svz;
        }
    }
}

extern "C" void kernel_launch(void* const* d_in, const int* in_sizes, int n_in,
                              void* d_out, int out_size, void* d_ws, size_t ws_size,
                              hipStream_t stream) {
    const float* pos    = (const float*)d_in[0];
    const float* cell   = (const float*)d_in[1];
    const float* cut    = (const float*)d_in[2];
    const int*   shifts = (const int*)d_in[3];
    const int*   ml     = (const int*)d_in[4];
    const int*   mm     = (const int*)d_in[5];

    int n_ml = in_sizes[4];
    int n_mm = in_sizes[5];
    int S    = in_sizes[3] / 3;
    int P0   = n_ml * n_mm;          // 128*8192 = 1048576
    int P    = (S + 1) * P0;         // 14*P0 = 14,680,064 ; out_size == 16*P

    int threads = P / 4;             // 4 pairs per thread -> 3,670,016
    int grid = (threads + 255) / 256;
    nl_kernel<<<grid, 256, 0, stream>>>(pos, cell, cut, shifts, ml, mm,
                                        (float*)d_out, n_mm, P0, P);
}